// Round 1
// baseline (369.890 us; speedup 1.0000x reference)
//
#include <hip/hip_runtime.h>
#include <hip/hip_bf16.h>

typedef __attribute__((ext_vector_type(8))) short  short8;
typedef __attribute__((ext_vector_type(4))) float  f32x4;

#define ALPHA 0.1f

__device__ __forceinline__ unsigned short f2bf(float f) {
    unsigned int u = __float_as_uint(f);
    u = (u + 0x7FFFu + ((u >> 16) & 1u)) >> 16;   // RNE
    return (unsigned short)u;
}

__device__ __forceinline__ f32x4 mfma16(short8 a, short8 b, f32x4 c) {
    return __builtin_amdgcn_mfma_f32_16x16x32_bf16(a, b, c, 0, 0, 0);
}

// ---- ws layout (bytes) ----
// P:     float  [4][256][128]  = x@W1x + y@W1y + b1        (524288 B)
// W1rT:  ushort [128][64]      W1rT[h][e] = W1[96+e][h]    (16384 B)
// W2T:   ushort [128][128]     W2T[n][k]  = W2[k][n]       (32768 B)
// W3T:   ushort [64][128]      W3T[e][h]  = W3[h][e]       (16384 B)
// ATTC:  ushort [4][256][256]                              (524288 B)
// ATTQ:  ushort [4][256][256]                              (524288 B)
#define WS_P     0u
#define WS_W1RT  524288u
#define WS_W2T   540672u
#define WS_W3T   573440u
#define WS_ATTC  589824u
#define WS_ATTQ  1114112u

__global__ __launch_bounds__(256) void prep_kernel(
    const float* __restrict__ x, const float* __restrict__ y,
    const float* __restrict__ cat, const float* __restrict__ qat,
    const float* __restrict__ W1, const float* __restrict__ b1,
    const float* __restrict__ W2, const float* __restrict__ W3,
    unsigned char* __restrict__ ws)
{
    unsigned int t = blockIdx.x * 256u + threadIdx.x;
    float* P = (float*)(ws + WS_P);
    unsigned short* W1rT = (unsigned short*)(ws + WS_W1RT);
    unsigned short* W2T  = (unsigned short*)(ws + WS_W2T);
    unsigned short* W3T  = (unsigned short*)(ws + WS_W3T);
    unsigned short* AC   = (unsigned short*)(ws + WS_ATTC);
    unsigned short* AQ   = (unsigned short*)(ws + WS_ATTQ);

    if (t < 131072u) {                       // P[b*256+j][h]
        unsigned int h = t & 127u, bj = t >> 7;
        float acc = b1[h];
        const float* xp = x + bj * 64u;
        const float* yp = y + bj * 32u;
        #pragma unroll 8
        for (int d = 0; d < 64; ++d) acc += xp[d] * W1[d * 128 + h];
        #pragma unroll 8
        for (int d = 0; d < 32; ++d) acc += yp[d] * W1[(64 + d) * 128 + h];
        P[t] = acc;
    } else if (t < 139264u) {                // W1rT (8192)
        unsigned int w = t - 131072u, h = w >> 6, e = w & 63u;
        W1rT[w] = f2bf(W1[(96u + e) * 128u + h]);
    } else if (t < 155648u) {                // W2T (16384)
        unsigned int w = t - 139264u, n = w >> 7, k2 = w & 127u;
        W2T[w] = f2bf(W2[k2 * 128u + n]);
    } else if (t < 163840u) {                // W3T (8192)
        unsigned int w = t - 155648u, e = w >> 7, h = w & 127u;
        W3T[w] = f2bf(W3[h * 64u + e]);
    } else if (t < 425984u) {                // ATTC (262144)
        unsigned int w = t - 163840u;
        AC[w] = f2bf(cat[w]);
    } else if (t < 688128u) {                // ATTQ (262144)
        unsigned int w = t - 425984u;
        AQ[w] = f2bf(qat[w]);
    }
}

// One block per (b,k). 4 waves; wave w owns rows [16w,16w+16) of each
// 64-row chunk (MLP phases barrier-free), then 64 rows of the att GEMMs.
__global__ __launch_bounds__(256) void fused_kernel(
    const float* __restrict__ rc, const float* __restrict__ rq,
    const float* __restrict__ b2, const float* __restrict__ b3,
    const unsigned char* __restrict__ ws,
    float* __restrict__ out_rc, float* __restrict__ out_rq)
{
    const float* P = (const float*)(ws + WS_P);
    const unsigned short* W1rT = (const unsigned short*)(ws + WS_W1RT);
    const unsigned short* W2T  = (const unsigned short*)(ws + WS_W2T);
    const unsigned short* W3T  = (const unsigned short*)(ws + WS_W3T);
    const unsigned short* AC   = (const unsigned short*)(ws + WS_ATTC);
    const unsigned short* AQ   = (const unsigned short*)(ws + WS_ATTQ);

    __shared__ unsigned short sH[64][136];    // H1/H2 strips (in-place), +8 pad
    __shared__ unsigned short sUT[64][264];   // U transposed: [e][j], +8 pad

    const int tid  = threadIdx.x;
    const int lane = tid & 63;
    const int wid  = tid >> 6;
    const int l15  = lane & 15;
    const int lg   = lane >> 4;
    const int b    = blockIdx.y;
    const int k    = blockIdx.x;

    const size_t bk = (size_t)(b * 256 + k);
    const float* rcb = rc + bk * (256 * 64);
    const float* rqb = rq + bk * (256 * 64);
    const float* Pb  = P + b * (256 * 128);

    float b2v[8], b3v[4];
    #pragma unroll
    for (int ct = 0; ct < 8; ++ct) b2v[ct] = b2[16 * ct + l15];
    #pragma unroll
    for (int ct = 0; ct < 4; ++ct) b3v[ct] = b3[16 * ct + l15];

    // ---------------- MLP: 4 chunks of 64 rows ----------------
    for (int jc = 0; jc < 4; ++jc) {
        const int jbase = jc * 64 + 16 * wid;   // this wave's global row base

        // phase A: H1 = relu(rc_chunk @ W1r + P)   K=64
        f32x4 accA[8];
        #pragma unroll
        for (int ct = 0; ct < 8; ++ct) accA[ct] = (f32x4)0.f;
        #pragma unroll
        for (int ks = 0; ks < 2; ++ks) {
            const float* ap = rcb + (jbase + l15) * 64 + 32 * ks + 8 * lg;
            f32x4 a0 = *(const f32x4*)ap;
            f32x4 a1 = *(const f32x4*)(ap + 4);
            short8 af;
            #pragma unroll
            for (int i = 0; i < 4; ++i) {
                af[i]     = (short)f2bf(a0[i]);
                af[4 + i] = (short)f2bf(a1[i]);
            }
            #pragma unroll
            for (int ct = 0; ct < 8; ++ct) {
                short8 bf = *(const short8*)(W1rT + (16 * ct + l15) * 64 + 32 * ks + 8 * lg);
                accA[ct] = mfma16(af, bf, accA[ct]);
            }
        }
        #pragma unroll
        for (int ct = 0; ct < 8; ++ct) {
            #pragma unroll
            for (int r = 0; r < 4; ++r) {
                int j = jbase + 4 * lg + r;
                float v = accA[ct][r] + Pb[j * 128 + 16 * ct + l15];
                v = fmaxf(v, 0.f);
                sH[16 * wid + 4 * lg + r][16 * ct + l15] = f2bf(v);
            }
        }

        // phase B: H2 = relu(H1 @ W2 + b2)   K=128, in-place (wave-private rows)
        f32x4 accB[8];
        #pragma unroll
        for (int ct = 0; ct < 8; ++ct) accB[ct] = (f32x4)0.f;
        #pragma unroll
        for (int ks = 0; ks < 4; ++ks) {
            short8 af = *(const short8*)(&sH[16 * wid + l15][32 * ks + 8 * lg]);
            #pragma unroll
            for (int ct = 0; ct < 8; ++ct) {
                short8 bf = *(const short8*)(W2T + (16 * ct + l15) * 128 + 32 * ks + 8 * lg);
                accB[ct] = mfma16(af, bf, accB[ct]);
            }
        }
        #pragma unroll
        for (int ct = 0; ct < 8; ++ct) {
            #pragma unroll
            for (int r = 0; r < 4; ++r) {
                float v = accB[ct][r] + b2v[ct];
                v = fmaxf(v, 0.f);
                sH[16 * wid + 4 * lg + r][16 * ct + l15] = f2bf(v);
            }
        }

        // phase C: U = H2 @ W3 + b3   K=128, N=64 -> sUT[e][j]
        f32x4 accC[4];
        #pragma unroll
        for (int ct = 0; ct < 4; ++ct) accC[ct] = (f32x4)0.f;
        #pragma unroll
        for (int ks = 0; ks < 4; ++ks) {
            short8 af = *(const short8*)(&sH[16 * wid + l15][32 * ks + 8 * lg]);
            #pragma unroll
            for (int ct = 0; ct < 4; ++ct) {
                short8 bf = *(const short8*)(W3T + (16 * ct + l15) * 128 + 32 * ks + 8 * lg);
                accC[ct] = mfma16(af, bf, accC[ct]);
            }
        }
        #pragma unroll
        for (int ct = 0; ct < 4; ++ct) {
            #pragma unroll
            for (int r = 0; r < 4; ++r) {
                float v = accC[ct][r] + b3v[ct];
                sUT[16 * ct + l15][jc * 64 + 16 * wid + 4 * lg + r] = f2bf(v);
            }
        }
    }

    __syncthreads();   // sUT complete

    // ---------------- attention GEMMs: M=256 (64 rows/wave), K=256, N=64 ----------------
    const unsigned short* acb = AC + b * 65536;
    const unsigned short* aqb = AQ + b * 65536;
    const int i0 = 64 * wid;

    // delta_r_c
    {
        f32x4 acc[4][4];
        #pragma unroll
        for (int rt = 0; rt < 4; ++rt)
            #pragma unroll
            for (int ct = 0; ct < 4; ++ct) acc[rt][ct] = (f32x4)0.f;
        for (int ks = 0; ks < 8; ++ks) {
            short8 bfr[4];
            #pragma unroll
            for (int ct = 0; ct < 4; ++ct)
                bfr[ct] = *(const short8*)(&sUT[16 * ct + l15][32 * ks + 8 * lg]);
            #pragma unroll
            for (int rt = 0; rt < 4; ++rt) {
                short8 af = *(const short8*)(acb + (i0 + 16 * rt + l15) * 256 + 32 * ks + 8 * lg);
                #pragma unroll
                for (int ct = 0; ct < 4; ++ct)
                    acc[rt][ct] = mfma16(af, bfr[ct], acc[rt][ct]);
            }
        }
        #pragma unroll
        for (int rt = 0; rt < 4; ++rt) {
            #pragma unroll
            for (int ct = 0; ct < 4; ++ct) {
                #pragma unroll
                for (int r = 0; r < 4; ++r) {
                    int i = i0 + 16 * rt + 4 * lg + r;
                    int e = 16 * ct + l15;
                    size_t off = bk * 16384 + i * 64 + e;
                    out_rc[off] = rcb[i * 64 + e] - ALPHA * acc[rt][ct][r];
                }
            }
        }
    }

    // delta_r_q
    {
        f32x4 acc[4][4];
        #pragma unroll
        for (int rt = 0; rt < 4; ++rt)
            #pragma unroll
            for (int ct = 0; ct < 4; ++ct) acc[rt][ct] = (f32x4)0.f;
        for (int ks = 0; ks < 8; ++ks) {
            short8 bfr[4];
            #pragma unroll
            for (int ct = 0; ct < 4; ++ct)
                bfr[ct] = *(const short8*)(&sUT[16 * ct + l15][32 * ks + 8 * lg]);
            #pragma unroll
            for (int rt = 0; rt < 4; ++rt) {
                short8 af = *(const short8*)(aqb + (i0 + 16 * rt + l15) * 256 + 32 * ks + 8 * lg);
                #pragma unroll
                for (int ct = 0; ct < 4; ++ct)
                    acc[rt][ct] = mfma16(af, bfr[ct], acc[rt][ct]);
            }
        }
        #pragma unroll
        for (int rt = 0; rt < 4; ++rt) {
            #pragma unroll
            for (int ct = 0; ct < 4; ++ct) {
                #pragma unroll
                for (int r = 0; r < 4; ++r) {
                    int i = i0 + 16 * rt + 4 * lg + r;
                    int e = 16 * ct + l15;
                    size_t off = bk * 16384 + i * 64 + e;
                    out_rq[off] = rqb[i * 64 + e] - ALPHA * acc[rt][ct][r];
                }
            }
        }
    }
}

extern "C" void kernel_launch(void* const* d_in, const int* in_sizes, int n_in,
                              void* d_out, int out_size, void* d_ws, size_t ws_size,
                              hipStream_t stream)
{
    const float* x   = (const float*)d_in[0];
    const float* y   = (const float*)d_in[1];
    const float* rc  = (const float*)d_in[2];
    const float* rq  = (const float*)d_in[3];
    const float* cat = (const float*)d_in[4];
    const float* qat = (const float*)d_in[5];
    const float* W1  = (const float*)d_in[6];
    const float* b1  = (const float*)d_in[7];
    const float* W2  = (const float*)d_in[8];
    const float* b2  = (const float*)d_in[9];
    const float* W3  = (const float*)d_in[10];
    const float* b3  = (const float*)d_in[11];

    float* out_rc = (float*)d_out;
    float* out_rq = out_rc + (size_t)4 * 256 * 256 * 64;
    unsigned char* ws = (unsigned char*)d_ws;

    prep_kernel<<<2688, 256, 0, stream>>>(x, y, cat, qat, W1, b1, W2, W3, ws);
    fused_kernel<<<dim3(256, 4), 256, 0, stream>>>(rc, rq, b2, b3, ws, out_rc, out_rq);
}